// Round 2
// baseline (379.616 us; speedup 1.0000x reference)
//
#include <hip/hip_runtime.h>

typedef __attribute__((ext_vector_type(8))) short short8;
typedef __attribute__((ext_vector_type(4))) float f32x4;
typedef __attribute__((ext_vector_type(4))) unsigned short ushort4v;

#define HIDDEN 1024
#define NHEAD 16
#define HD 64
#define BATCH 2
#define SEQ 2048
#define MROWS (BATCH * SEQ)  // 4096

__device__ __forceinline__ unsigned short f2b(float f) {
  union { float f; unsigned u; } v; v.f = f;
  unsigned r = v.u + 0x7fffu + ((v.u >> 16) & 1u);
  return (unsigned short)(r >> 16);
}

__device__ __forceinline__ unsigned cvt_pk_bf16(float lo, float hi) {
  unsigned r;
  asm("v_cvt_pk_bf16_f32 %0, %1, %2" : "=v"(r) : "v"(lo), "v"(hi));
  return r;
}

// ---------------- f32 -> bf16 convert ----------------
__global__ void cvt_bf16_kernel(const float* __restrict__ in,
                                unsigned short* __restrict__ out, int n) {
  int i = (blockIdx.x * blockDim.x + threadIdx.x) * 4;
  if (i >= n) return;
  float4 v = *reinterpret_cast<const float4*>(in + i);
  ushort4v o;
  o.x = f2b(v.x); o.y = f2b(v.y); o.z = f2b(v.z); o.w = f2b(v.w);
  *reinterpret_cast<ushort4v*>(out + i) = o;
}

// ---------------- GEMM: C[M][N] = A[M][K] * B[N][K]^T (+bias), mode epilogue ----
// mode 0: Q -> bf16 [B,H,S,D], (acc+bias)*0.125
// mode 1: K -> bf16 [B,H,S,D]
// mode 2: V -> bf16 [B,H,D,S] (transposed)
// mode 3: O -> f32 [M][N] to d_out
__global__ __launch_bounds__(256) void gemm_bt_kernel(
    const unsigned short* __restrict__ A, const unsigned short* __restrict__ Bm,
    const float* __restrict__ bias, void* __restrict__ outp, int M, int K,
    int mode) {
  __shared__ unsigned short Al[64][72];  // +8 pad: row stride 144B (16B-aligned)
  __shared__ unsigned short Bl[64][72];
  const int t = threadIdx.x;
  const int w = t >> 6;
  const int l = t & 63;
  const int m0 = blockIdx.x * 64;
  const int n0 = blockIdx.y * 64;

  f32x4 acc[4];
#pragma unroll
  for (int f = 0; f < 4; ++f) acc[f] = f32x4{0.f, 0.f, 0.f, 0.f};

  for (int kt = 0; kt < K; kt += 64) {
    __syncthreads();
#pragma unroll
    for (int p = 0; p < 2; ++p) {
      int idx = p * 256 + t;
      int row = idx >> 3, cb = idx & 7;
      *reinterpret_cast<short8*>(&Al[row][cb * 8]) =
          *reinterpret_cast<const short8*>(A + (size_t)(m0 + row) * K + kt + cb * 8);
      *reinterpret_cast<short8*>(&Bl[row][cb * 8]) =
          *reinterpret_cast<const short8*>(Bm + (size_t)(n0 + row) * K + kt + cb * 8);
    }
    __syncthreads();
#pragma unroll
    for (int kk = 0; kk < 2; ++kk) {
      short8 af = *reinterpret_cast<const short8*>(&Al[w * 16 + (l & 15)][kk * 32 + (l >> 4) * 8]);
#pragma unroll
      for (int f = 0; f < 4; ++f) {
        short8 bf = *reinterpret_cast<const short8*>(&Bl[f * 16 + (l & 15)][kk * 32 + (l >> 4) * 8]);
        acc[f] = __builtin_amdgcn_mfma_f32_16x16x32_bf16(af, bf, acc[f], 0, 0, 0);
      }
    }
  }

#pragma unroll
  for (int f = 0; f < 4; ++f)
#pragma unroll
    for (int j = 0; j < 4; ++j) {
      int m = m0 + w * 16 + (l >> 4) * 4 + j;
      int n = n0 + f * 16 + (l & 15);
      float v = acc[f][j] + bias[n];
      if (mode <= 1) {
        if (mode == 0) v *= 0.125f;  // 1/sqrt(64)
        int b = m >> 11, s = m & 2047, h = n >> 6, d = n & 63;
        ((unsigned short*)outp)[((size_t)(b * NHEAD + h) * SEQ + s) * HD + d] = f2b(v);
      } else if (mode == 2) {
        int b = m >> 11, s = m & 2047, h = n >> 6, d = n & 63;
        ((unsigned short*)outp)[((size_t)(b * NHEAD + h) * HD + d) * SEQ + s] = f2b(v);
      } else {
        ((float*)outp)[(size_t)m * HIDDEN + n] = v;
      }
    }
}

// ---------------- flash attention (swapped-operand, in-register softmax) ----
// Q,K: bf16 [B*H][S][64]; Vt: bf16 [B*H][64][S]; mask: int [B][S]
// O: bf16 [B*S][HIDDEN]
// Per wave: 16 q-rows. S^T = mfma(K_frag, Q_frag): lane holds
// S^T[k_local = f*16 + hi*4 + j][q = q0 + (lane&15)]  (hi = lane>>4).
// Softmax per q-column: in-lane tree over 16 regs + shfl_xor(16,32).
// P^T redistributed to PV B-frags via cvt_pk + ds_bpermute (no LDS, no barriers).
__global__ __launch_bounds__(256) void attn_kernel(
    const unsigned short* __restrict__ Q, const unsigned short* __restrict__ Km,
    const unsigned short* __restrict__ Vt, const int* __restrict__ mask,
    unsigned short* __restrict__ O) {
  const int t = threadIdx.x;
  const int w = t >> 6;
  const int l = t & 63;
  const int hi = l >> 4;
  const int lo16 = l & 15;
  const int hi4 = hi << 2;
  const int bh = blockIdx.y;
  const int b = bh >> 4, h = bh & 15;
  const int q0 = blockIdx.x * 64 + w * 16;
  const int qrow = q0 + lo16;

  const unsigned short* Qb = Q + (size_t)bh * SEQ * HD;
  const unsigned short* Kb = Km + (size_t)bh * SEQ * HD;
  const unsigned short* Vb = Vt + (size_t)bh * HD * SEQ;
  const int* mb = mask + b * SEQ;

  // Q fragment (B-operand of swapped QK^T): Q[q=lane&15][d = hi*8 + 0..7]
  short8 qf[2];
#pragma unroll
  for (int kk = 0; kk < 2; ++kk)
    qf[kk] = *reinterpret_cast<const short8*>(Qb + (size_t)(q0 + lo16) * HD + kk * 32 + hi * 8);

  f32x4 o_acc[4];  // out^T[d = f*16 + hi*4 + j][q]
#pragma unroll
  for (int f = 0; f < 4; ++f) o_acc[f] = f32x4{0.f, 0.f, 0.f, 0.f};
  float mrow = -1e30f, srow = 0.f;

  for (int k0 = 0; k0 < SEQ; k0 += 64) {
    // ---- QK^T (swapped): sc[f] = S^T[k = k0 + f*16 + hi*4 + j][q]
    f32x4 sc[4];
#pragma unroll
    for (int f = 0; f < 4; ++f) sc[f] = f32x4{0.f, 0.f, 0.f, 0.f};
#pragma unroll
    for (int kk = 0; kk < 2; ++kk)
#pragma unroll
      for (int f = 0; f < 4; ++f) {
        short8 kf = *reinterpret_cast<const short8*>(
            Kb + (size_t)(k0 + f * 16 + lo16) * HD + kk * 32 + hi * 8);
        sc[f] = __builtin_amdgcn_mfma_f32_16x16x32_bf16(kf, qf[kk], sc[f], 0, 0, 0);
      }

    // ---- mask (additive -1e30, diagonal k==q exempt) + tile max
    float fm[4];
#pragma unroll
    for (int f = 0; f < 4; ++f) {
      int4 mi = *reinterpret_cast<const int4*>(mb + k0 + f * 16 + hi4);
      int kbase = k0 + f * 16 + hi4;
      float v0 = sc[f][0] + ((mi.x && (kbase + 0) != qrow) ? -1e30f : 0.f);
      float v1 = sc[f][1] + ((mi.y && (kbase + 1) != qrow) ? -1e30f : 0.f);
      float v2 = sc[f][2] + ((mi.z && (kbase + 2) != qrow) ? -1e30f : 0.f);
      float v3 = sc[f][3] + ((mi.w && (kbase + 3) != qrow) ? -1e30f : 0.f);
      sc[f][0] = v0; sc[f][1] = v1; sc[f][2] = v2; sc[f][3] = v3;
      fm[f] = fmaxf(fmaxf(v0, v1), fmaxf(v2, v3));
    }
    float mx = fmaxf(fmaxf(fm[0], fm[1]), fmaxf(fm[2], fm[3]));
    mx = fmaxf(mx, __shfl_xor(mx, 16, 64));
    mx = fmaxf(mx, __shfl_xor(mx, 32, 64));

    float mnew = fmaxf(mrow, mx);
    float pscale = __expf(mrow - mnew);
    mrow = mnew;

    // ---- P = exp(S - m), tile sum
    float fs[4];
#pragma unroll
    for (int f = 0; f < 4; ++f) {
      float p0 = __expf(sc[f][0] - mnew);
      float p1 = __expf(sc[f][1] - mnew);
      float p2 = __expf(sc[f][2] - mnew);
      float p3 = __expf(sc[f][3] - mnew);
      sc[f][0] = p0; sc[f][1] = p1; sc[f][2] = p2; sc[f][3] = p3;
      fs[f] = (p0 + p1) + (p2 + p3);
    }
    float sum = (fs[0] + fs[1]) + (fs[2] + fs[3]);
    sum += __shfl_xor(sum, 16, 64);
    sum += __shfl_xor(sum, 32, 64);
    srow = srow * pscale + sum;
#pragma unroll
    for (int f = 0; f < 4; ++f)
#pragma unroll
      for (int j = 0; j < 4; ++j) o_acc[f][j] *= pscale;

    // ---- pack P^T to bf16 pairs: c[f][m] covers k = f*16 + hi*4 + {2m, 2m+1}
    unsigned c[4][2];
#pragma unroll
    for (int f = 0; f < 4; ++f) {
      c[f][0] = cvt_pk_bf16(sc[f][0], sc[f][1]);
      c[f][1] = cvt_pk_bf16(sc[f][2], sc[f][3]);
    }

    // ---- PV (swapped): o^T = mfma(V^T_frag, P^T_frag)
    // B-frag for mfma g needs, at lane (hi,q): k = g*32 + hi*8 + 2t + {0,1}
    //   source: frag f = 2g + (hi>>1), dword m = t&1,
    //   src lane = q + 16*(2*(hi&1) + (t>>1))
    const int fsel = hi >> 1;  // 0: use c[2g], 1: use c[2g+1]
#pragma unroll
    for (int g = 0; g < 2; ++g) {
      union { unsigned u[4]; short8 s8; } pb;
#pragma unroll
      for (int tt = 0; tt < 4; ++tt) {
        int src = lo16 + 16 * (2 * (hi & 1) + (tt >> 1));
        unsigned v0 = __shfl(c[2 * g + 0][tt & 1], src, 64);
        unsigned v1 = __shfl(c[2 * g + 1][tt & 1], src, 64);
        pb.u[tt] = fsel ? v1 : v0;
      }
#pragma unroll
      for (int f = 0; f < 4; ++f) {
        short8 av = *reinterpret_cast<const short8*>(
            Vb + (size_t)(f * 16 + lo16) * SEQ + k0 + g * 32 + hi * 8);
        o_acc[f] = __builtin_amdgcn_mfma_f32_16x16x32_bf16(av, pb.s8, o_acc[f], 0, 0, 0);
      }
    }
  }

  // ---- epilogue: O[b, q, h*64 + d] = o^T[d][q] / srow
  float rinv = 1.f / srow;
#pragma unroll
  for (int f = 0; f < 4; ++f)
#pragma unroll
    for (int j = 0; j < 4; ++j) {
      int d = f * 16 + hi4 + j;
      O[(size_t)(b * SEQ + qrow) * HIDDEN + h * HD + d] = f2b(o_acc[f][j] * rinv);
    }
}

// ---------------- launch ----------------
extern "C" void kernel_launch(void* const* d_in, const int* in_sizes, int n_in,
                              void* d_out, int out_size, void* d_ws,
                              size_t ws_size, hipStream_t stream) {
  const float* x = (const float*)d_in[0];
  const int* mask = (const int*)d_in[1];
  const float* Wq = (const float*)d_in[2];
  const float* bq = (const float*)d_in[3];
  const float* Wk = (const float*)d_in[4];
  const float* bk = (const float*)d_in[5];
  const float* Wv = (const float*)d_in[6];
  const float* bv = (const float*)d_in[7];
  const float* Wo = (const float*)d_in[8];
  const float* bo = (const float*)d_in[9];

  char* ws = (char*)d_ws;
  unsigned short* xb  = (unsigned short*)(ws + ((size_t)0 << 20));   // 8 MB
  unsigned short* wqb = (unsigned short*)(ws + ((size_t)8 << 20));   // 2 MB
  unsigned short* wkb = (unsigned short*)(ws + ((size_t)10 << 20));
  unsigned short* wvb = (unsigned short*)(ws + ((size_t)12 << 20));
  unsigned short* wob = (unsigned short*)(ws + ((size_t)14 << 20));
  unsigned short* qw  = (unsigned short*)(ws + ((size_t)16 << 20));  // 8 MB
  unsigned short* kw  = (unsigned short*)(ws + ((size_t)24 << 20));
  unsigned short* vtw = (unsigned short*)(ws + ((size_t)32 << 20));
  unsigned short* ow  = (unsigned short*)(ws + ((size_t)40 << 20));

  const int nx = MROWS * HIDDEN;
  const int nw = HIDDEN * HIDDEN;
  cvt_bf16_kernel<<<nx / 4 / 256, 256, 0, stream>>>(x, xb, nx);
  cvt_bf16_kernel<<<nw / 4 / 256, 256, 0, stream>>>(Wq, wqb, nw);
  cvt_bf16_kernel<<<nw / 4 / 256, 256, 0, stream>>>(Wk, wkb, nw);
  cvt_bf16_kernel<<<nw / 4 / 256, 256, 0, stream>>>(Wv, wvb, nw);
  cvt_bf16_kernel<<<nw / 4 / 256, 256, 0, stream>>>(Wo, wob, nw);

  dim3 gg(MROWS / 64, HIDDEN / 64);
  gemm_bt_kernel<<<gg, 256, 0, stream>>>(xb, wqb, bq, qw, MROWS, HIDDEN, 0);
  gemm_bt_kernel<<<gg, 256, 0, stream>>>(xb, wkb, bk, kw, MROWS, HIDDEN, 1);
  gemm_bt_kernel<<<gg, 256, 0, stream>>>(xb, wvb, bv, vtw, MROWS, HIDDEN, 2);

  attn_kernel<<<dim3(SEQ / 64, BATCH * NHEAD), 256, 0, stream>>>(qw, kw, vtw, mask, ow);

  gemm_bt_kernel<<<gg, 256, 0, stream>>>(ow, wob, bo, d_out, MROWS, HIDDEN, 3);
}

// Round 3
// 178.263 us; speedup vs baseline: 2.1295x; 2.1295x over previous
//
#include <hip/hip_runtime.h>

typedef __attribute__((ext_vector_type(8))) short short8;
typedef __attribute__((ext_vector_type(4))) float f32x4;
typedef __attribute__((ext_vector_type(4))) unsigned short ushort4v;

#define HIDDEN 1024
#define NHEAD 16
#define HD 64
#define BATCH 2
#define SEQ 2048
#define MROWS (BATCH * SEQ)  // 4096

__device__ __forceinline__ unsigned short f2b(float f) {
  union { float f; unsigned u; } v; v.f = f;
  unsigned r = v.u + 0x7fffu + ((v.u >> 16) & 1u);
  return (unsigned short)(r >> 16);
}

__device__ __forceinline__ unsigned cvt_pk_bf16(float lo, float hi) {
  unsigned r;
  asm("v_cvt_pk_bf16_f32 %0, %1, %2" : "=v"(r) : "v"(lo), "v"(hi));
  return r;
}

// async global->LDS, 16B per lane; LDS dest = wave-uniform base + lane*16
__device__ __forceinline__ void gll16(const void* g, void* l) {
  __builtin_amdgcn_global_load_lds(
      (__attribute__((address_space(1))) void*)g,
      (__attribute__((address_space(3))) void*)l, 16, 0, 0);
}

// ---------------- f32 -> bf16 convert ----------------
__global__ void cvt_bf16_kernel(const float* __restrict__ in,
                                unsigned short* __restrict__ out, int n) {
  int i = (blockIdx.x * blockDim.x + threadIdx.x) * 4;
  if (i >= n) return;
  float4 v = *reinterpret_cast<const float4*>(in + i);
  ushort4v o;
  o.x = f2b(v.x); o.y = f2b(v.y); o.z = f2b(v.z); o.w = f2b(v.w);
  *reinterpret_cast<ushort4v*>(out + i) = o;
}

// ---------------- 128x128 GEMM, BK=64, global_load_lds staging ----------------
// C[M][N] = A[M][K] * W[N][K]^T + bias.
// MODE 0: fused QKV (N=3072; region = n0>>10 selects W0/W1/W2, writes q/k/vt)
// MODE 1: O-projection (f32 out to o0)
// LDS layout: linear [128 rows][64 elems]; chunk c of row r holds global
// chunk c ^ (r&7)  (pre-swizzled source; reads XOR the same key).
template <int MODE>
__global__ __launch_bounds__(256) void gemm128_kernel(
    const unsigned short* __restrict__ A,
    const unsigned short* __restrict__ W0,
    const unsigned short* __restrict__ W1,
    const unsigned short* __restrict__ W2,
    const float* __restrict__ c0, const float* __restrict__ c1,
    const float* __restrict__ c2, void* __restrict__ o0,
    void* __restrict__ o1, void* __restrict__ o2) {
  __shared__ __align__(16) unsigned short Al[128 * 64];
  __shared__ __align__(16) unsigned short Bl[128 * 64];
  const int t = threadIdx.x;
  const int w = t >> 6, l = t & 63;
  const int hi = l >> 4, lo16 = l & 15;
  const int wr = w >> 1, wc = w & 1;
  const int m0 = blockIdx.x * 128;
  const int n0 = blockIdx.y * 128;
  const int K = HIDDEN;

  const unsigned short* Bsel;
  const float* bias;
  int region = 0, n_loc = n0;
  if (MODE == 0) {
    region = n0 >> 10;
    n_loc = n0 & 1023;
    Bsel = region == 0 ? W0 : (region == 1 ? W1 : W2);
    bias = region == 0 ? c0 : (region == 1 ? c1 : c2);
  } else {
    Bsel = W0;
    bias = c0;
  }

  const int srow = w * 32 + (l >> 3);      // staging row (per inst +8)
  const int schunk = (l & 7) ^ (l >> 3);   // pre-swizzled source chunk
  const int rsw = (lo16 & 7);              // read-side swizzle key

  f32x4 acc[4][4];
#pragma unroll
  for (int mi = 0; mi < 4; ++mi)
#pragma unroll
    for (int f = 0; f < 4; ++f) acc[mi][f] = f32x4{0.f, 0.f, 0.f, 0.f};

  for (int kt = 0; kt < K; kt += 64) {
    __syncthreads();  // prior tile's ds_reads done before overwrite
#pragma unroll
    for (int i = 0; i < 4; ++i) {
      int r = srow + i * 8;
      gll16(A + (size_t)(m0 + r) * K + kt + schunk * 8,
            &Al[(w * 32 + i * 8) * 64]);
      gll16(Bsel + (size_t)(n_loc + r) * K + kt + schunk * 8,
            &Bl[(w * 32 + i * 8) * 64]);
    }
    __syncthreads();  // vmcnt(0) drain + barrier: tile visible
#pragma unroll
    for (int kk = 0; kk < 2; ++kk) {
      short8 af[4], bf[4];
#pragma unroll
      for (int mi = 0; mi < 4; ++mi) {
        int row = wr * 64 + mi * 16 + lo16;
        af[mi] = *reinterpret_cast<const short8*>(
            &Al[row * 64 + (((kk * 4 + hi) ^ rsw) * 8)]);
      }
#pragma unroll
      for (int f = 0; f < 4; ++f) {
        int row = wc * 64 + f * 16 + lo16;
        bf[f] = *reinterpret_cast<const short8*>(
            &Bl[row * 64 + (((kk * 4 + hi) ^ rsw) * 8)]);
      }
#pragma unroll
      for (int mi = 0; mi < 4; ++mi)
#pragma unroll
        for (int f = 0; f < 4; ++f)
          acc[mi][f] =
              __builtin_amdgcn_mfma_f32_16x16x32_bf16(af[mi], bf[f], acc[mi][f], 0, 0, 0);
    }
  }

#pragma unroll
  for (int mi = 0; mi < 4; ++mi)
#pragma unroll
    for (int f = 0; f < 4; ++f) {
      int mbase = m0 + wr * 64 + mi * 16 + hi * 4;
      int n_rel = n_loc + wc * 64 + f * 16 + lo16;  // 0..1023
      float bv_ = bias[n_rel];
#pragma unroll
      for (int j = 0; j < 4; ++j) {
        float v = acc[mi][f][j] + bv_;
        int mm = mbase + j;
        if (MODE == 0) {
          int b = mm >> 11, s = mm & 2047, h = n_rel >> 6, d = n_rel & 63;
          if (region == 0)
            ((unsigned short*)o0)[((size_t)(b * NHEAD + h) * SEQ + s) * HD + d] =
                f2b(v * 0.125f);
          else if (region == 1)
            ((unsigned short*)o1)[((size_t)(b * NHEAD + h) * SEQ + s) * HD + d] =
                f2b(v);
          else
            ((unsigned short*)o2)[((size_t)(b * NHEAD + h) * HD + d) * SEQ + s] =
                f2b(v);
        } else {
          ((float*)o0)[(size_t)mm * HIDDEN + n_rel] = v;
        }
      }
    }
}

// ---------------- flash attention (LDS-staged K/V, in-register softmax) ----
// Q,K: bf16 [B*H][S][64]; Vt: bf16 [B*H][64][S]; mask: int [B][S]
// Per block: 64 q-rows (4 waves x 16). K/V tiles (64x64) double-buffered in
// LDS via global_load_lds (shared by all 4 waves), swizzled chunk ^= row&7.
__global__ __launch_bounds__(256) void attn_kernel(
    const unsigned short* __restrict__ Q, const unsigned short* __restrict__ Km,
    const unsigned short* __restrict__ Vt, const int* __restrict__ mask,
    unsigned short* __restrict__ O) {
  __shared__ __align__(16) unsigned short Kl[2][64 * 64];
  __shared__ __align__(16) unsigned short Vl[2][64 * 64];
  const int t = threadIdx.x;
  const int w = t >> 6, l = t & 63;
  const int hi = l >> 4, lo16 = l & 15;
  const int hi4 = hi << 2;
  const int bh = blockIdx.y;
  const int b = bh >> 4, h = bh & 15;
  const int q0 = blockIdx.x * 64 + w * 16;
  const int qrow = q0 + lo16;

  const unsigned short* Qb = Q + (size_t)bh * SEQ * HD;
  const unsigned short* Kb = Km + (size_t)bh * SEQ * HD;
  const unsigned short* Vb = Vt + (size_t)bh * HD * SEQ;
  const int* mb = mask + b * SEQ;

  const int srow = w * 16 + (l >> 3);     // staging row (per inst +8)
  const int schunk = (l & 7) ^ (l >> 3);  // pre-swizzled source chunk
  const int rsw = (lo16 & 7);             // read-side swizzle key

  // Q fragment (B-operand of swapped QK^T)
  short8 qf[2];
#pragma unroll
  for (int kk = 0; kk < 2; ++kk)
    qf[kk] = *reinterpret_cast<const short8*>(
        Qb + (size_t)(q0 + lo16) * HD + kk * 32 + hi * 8);

  f32x4 o_acc[4];
#pragma unroll
  for (int f = 0; f < 4; ++f) o_acc[f] = f32x4{0.f, 0.f, 0.f, 0.f};
  float mrow = -1e30f, srw = 0.f;

  // prologue: stage tile 0 into buf 0
#pragma unroll
  for (int i = 0; i < 2; ++i) {
    int r = srow + i * 8;
    gll16(Kb + (size_t)r * HD + schunk * 8, &Kl[0][(w * 16 + i * 8) * 64]);
    gll16(Vb + (size_t)r * SEQ + schunk * 8, &Vl[0][(w * 16 + i * 8) * 64]);
  }
  __syncthreads();

  int buf = 0;
  for (int k0 = 0; k0 < SEQ; k0 += 64) {
    // issue next-tile staging (async, drained by end-of-iter barrier)
    if (k0 + 64 < SEQ) {
      int kn = k0 + 64;
#pragma unroll
      for (int i = 0; i < 2; ++i) {
        int r = srow + i * 8;
        gll16(Kb + (size_t)(kn + r) * HD + schunk * 8,
              &Kl[buf ^ 1][(w * 16 + i * 8) * 64]);
        gll16(Vb + (size_t)r * SEQ + kn + schunk * 8,
              &Vl[buf ^ 1][(w * 16 + i * 8) * 64]);
      }
    }

    // ---- QK^T (swapped): sc[f] = S^T[k = k0 + f*16 + hi*4 + j][q]
    f32x4 sc[4];
#pragma unroll
    for (int f = 0; f < 4; ++f) sc[f] = f32x4{0.f, 0.f, 0.f, 0.f};
#pragma unroll
    for (int kk = 0; kk < 2; ++kk)
#pragma unroll
      for (int f = 0; f < 4; ++f) {
        short8 kf = *reinterpret_cast<const short8*>(
            &Kl[buf][(f * 16 + lo16) * 64 + (((kk * 4 + hi) ^ rsw) * 8)]);
        sc[f] = __builtin_amdgcn_mfma_f32_16x16x32_bf16(kf, qf[kk], sc[f], 0, 0, 0);
      }

    // ---- mask (additive -1e30, diagonal k==q exempt) + tile max
    float fm[4];
#pragma unroll
    for (int f = 0; f < 4; ++f) {
      int4 mi = *reinterpret_cast<const int4*>(mb + k0 + f * 16 + hi4);
      int kbase = k0 + f * 16 + hi4;
      float v0 = sc[f][0] + ((mi.x && (kbase + 0) != qrow) ? -1e30f : 0.f);
      float v1 = sc[f][1] + ((mi.y && (kbase + 1) != qrow) ? -1e30f : 0.f);
      float v2 = sc[f][2] + ((mi.z && (kbase + 2) != qrow) ? -1e30f : 0.f);
      float v3 = sc[f][3] + ((mi.w && (kbase + 3) != qrow) ? -1e30f : 0.f);
      sc[f][0] = v0; sc[f][1] = v1; sc[f][2] = v2; sc[f][3] = v3;
      fm[f] = fmaxf(fmaxf(v0, v1), fmaxf(v2, v3));
    }
    float mx = fmaxf(fmaxf(fm[0], fm[1]), fmaxf(fm[2], fm[3]));
    mx = fmaxf(mx, __shfl_xor(mx, 16, 64));
    mx = fmaxf(mx, __shfl_xor(mx, 32, 64));

    float mnew = fmaxf(mrow, mx);
    float pscale = __expf(mrow - mnew);
    mrow = mnew;

    // ---- P = exp(S - m), tile sum
    float fs[4];
#pragma unroll
    for (int f = 0; f < 4; ++f) {
      float p0 = __expf(sc[f][0] - mnew);
      float p1 = __expf(sc[f][1] - mnew);
      float p2 = __expf(sc[f][2] - mnew);
      float p3 = __expf(sc[f][3] - mnew);
      sc[f][0] = p0; sc[f][1] = p1; sc[f][2] = p2; sc[f][3] = p3;
      fs[f] = (p0 + p1) + (p2 + p3);
    }
    float sum = (fs[0] + fs[1]) + (fs[2] + fs[3]);
    sum += __shfl_xor(sum, 16, 64);
    sum += __shfl_xor(sum, 32, 64);
    srw = srw * pscale + sum;
#pragma unroll
    for (int f = 0; f < 4; ++f)
#pragma unroll
      for (int j = 0; j < 4; ++j) o_acc[f][j] *= pscale;

    // ---- pack P^T to bf16 pairs
    unsigned c[4][2];
#pragma unroll
    for (int f = 0; f < 4; ++f) {
      c[f][0] = cvt_pk_bf16(sc[f][0], sc[f][1]);
      c[f][1] = cvt_pk_bf16(sc[f][2], sc[f][3]);
    }

    // ---- PV (swapped): o^T = mfma(V^T_frag, P^T_frag)
    const int fsel = hi >> 1;
#pragma unroll
    for (int g = 0; g < 2; ++g) {
      union { unsigned u[4]; short8 s8; } pb;
#pragma unroll
      for (int tt = 0; tt < 4; ++tt) {
        int src = lo16 + 16 * (2 * (hi & 1) + (tt >> 1));
        unsigned v0 = __shfl(c[2 * g + 0][tt & 1], src, 64);
        unsigned v1 = __shfl(c[2 * g + 1][tt & 1], src, 64);
        pb.u[tt] = fsel ? v1 : v0;
      }
#pragma unroll
      for (int f = 0; f < 4; ++f) {
        short8 av = *reinterpret_cast<const short8*>(
            &Vl[buf][(f * 16 + lo16) * 64 + (((g * 4 + hi) ^ rsw) * 8)]);
        o_acc[f] = __builtin_amdgcn_mfma_f32_16x16x32_bf16(av, pb.s8, o_acc[f], 0, 0, 0);
      }
    }

    __syncthreads();  // drains this wave's staging vmcnt + LDS reads, all waves
    buf ^= 1;
  }

  // ---- epilogue
  float rinv = 1.f / srw;
#pragma unroll
  for (int f = 0; f < 4; ++f)
#pragma unroll
    for (int j = 0; j < 4; ++j) {
      int d = f * 16 + hi4 + j;
      O[(size_t)(b * SEQ + qrow) * HIDDEN + h * HD + d] = f2b(o_acc[f][j] * rinv);
    }
}

// ---------------- launch ----------------
extern "C" void kernel_launch(void* const* d_in, const int* in_sizes, int n_in,
                              void* d_out, int out_size, void* d_ws,
                              size_t ws_size, hipStream_t stream) {
  const float* x = (const float*)d_in[0];
  const int* mask = (const int*)d_in[1];
  const float* Wq = (const float*)d_in[2];
  const float* bq = (const float*)d_in[3];
  const float* Wk = (const float*)d_in[4];
  const float* bk = (const float*)d_in[5];
  const float* Wv = (const float*)d_in[6];
  const float* bv = (const float*)d_in[7];
  const float* Wo = (const float*)d_in[8];
  const float* bo = (const float*)d_in[9];

  char* ws = (char*)d_ws;
  unsigned short* xb  = (unsigned short*)(ws + ((size_t)0 << 20));   // 8 MB
  unsigned short* wqb = (unsigned short*)(ws + ((size_t)8 << 20));   // 2 MB
  unsigned short* wkb = (unsigned short*)(ws + ((size_t)10 << 20));
  unsigned short* wvb = (unsigned short*)(ws + ((size_t)12 << 20));
  unsigned short* wob = (unsigned short*)(ws + ((size_t)14 << 20));
  unsigned short* qw  = (unsigned short*)(ws + ((size_t)16 << 20));  // 8 MB
  unsigned short* kw  = (unsigned short*)(ws + ((size_t)24 << 20));
  unsigned short* vtw = (unsigned short*)(ws + ((size_t)32 << 20));
  unsigned short* ow  = (unsigned short*)(ws + ((size_t)40 << 20));

  const int nx = MROWS * HIDDEN;
  const int nw = HIDDEN * HIDDEN;
  cvt_bf16_kernel<<<nx / 4 / 256, 256, 0, stream>>>(x, xb, nx);
  cvt_bf16_kernel<<<nw / 4 / 256, 256, 0, stream>>>(Wq, wqb, nw);
  cvt_bf16_kernel<<<nw / 4 / 256, 256, 0, stream>>>(Wk, wkb, nw);
  cvt_bf16_kernel<<<nw / 4 / 256, 256, 0, stream>>>(Wv, wvb, nw);
  cvt_bf16_kernel<<<nw / 4 / 256, 256, 0, stream>>>(Wo, wob, nw);

  // fused QKV projection: [4096 x 3072]
  gemm128_kernel<0><<<dim3(MROWS / 128, 3 * HIDDEN / 128), 256, 0, stream>>>(
      xb, wqb, wkb, wvb, bq, bk, bv, qw, kw, vtw);

  attn_kernel<<<dim3(SEQ / 64, BATCH * NHEAD), 256, 0, stream>>>(qw, kw, vtw,
                                                                 mask, ow);

  // output projection: [4096 x 1024] f32
  gemm128_kernel<1><<<dim3(MROWS / 128, HIDDEN / 128), 256, 0, stream>>>(
      ow, wob, nullptr, nullptr, bo, nullptr, nullptr, d_out, nullptr, nullptr);
}